// Round 11
// baseline (379.771 us; speedup 1.0000x reference)
//
#include <hip/hip_runtime.h>
#include <hip/hip_bf16.h>

// Problem constants
#define N_SRC1 200000
#define N_TGT1 50000
#define N_TGT2 10000
#define E1_N   1000000
#define E2_N   300000
#define F_IN   256
#define F_HID  192
#define F_OUT  128

typedef __attribute__((ext_vector_type(4))) float f32x4;
typedef __attribute__((ext_vector_type(8))) short short8;

__device__ inline float bf2f(ushort u) {
    union { uint i; float f; } c; c.i = ((uint)u) << 16; return c.f;
}
__device__ inline ushort f2bf(float f) {
    union { float f; uint i; } c; c.f = f;
    uint u = c.i;
    return (ushort)((u + 0x7FFFu + ((u >> 16) & 1u)) >> 16);  // RNE
}
__device__ inline uint pack2(float a, float b) {
    return (uint)f2bf(a) | ((uint)f2bf(b) << 16);
}

#define HB1 3907   // (E1_N+255)/256
#define HB2 1172   // (E2_N+255)/256
#define NP1 196    // (N_TGT1+255)/256
#define NP2 40     // (N_TGT2+255)/256

// ---------------------------------------------------------------------------
// prep: blocks [0,2048): x f32->bf16; blocks [2048,2176): pack all weights
// (R4/R7-measured-good; do NOT fuse hist in — R5 regression)
// ---------------------------------------------------------------------------
__global__ __launch_bounds__(256) void prep(
    const float4* __restrict__ x4, uint2* __restrict__ xb,
    const float* __restrict__ Wl1, const float* __restrict__ Wr1,
    const float* __restrict__ Wl2, const float* __restrict__ Wr2,
    const float* __restrict__ W1, const float* __restrict__ W2,
    ushort* __restrict__ wc1, ushort* __restrict__ wc2,
    ushort* __restrict__ w1b, ushort* __restrict__ w2b)
{
    const int b = blockIdx.x, tid = threadIdx.x;
    if (b < 2048) {
        const int n4 = N_SRC1 * F_IN / 4;
        for (int i = b * 256 + tid; i < n4; i += 2048 * 256) {
            float4 v = x4[i];
            uint2 o;
            o.x = pack2(v.x, v.y);
            o.y = pack2(v.z, v.w);
            xb[i] = o;
        }
        return;
    }
    const int wt = (b - 2048) * 256 + tid;
    for (int idx = wt; idx < 233472; idx += 128 * 256) {
        if (idx < 98304) {                           // wc1: 192 x 512
            int n = idx >> 9, k = idx & 511;
            float v = (k < 256) ? Wl1[n * 256 + k] : Wr1[n * 256 + (k - 256)];
            wc1[idx] = f2bf(v);
        } else if (idx < 98304 + 73728) {            // wc2: 192 x 384
            int i2 = idx - 98304;
            int n = i2 / 384, k = i2 - n * 384;
            float v = (k < 192) ? Wl2[n * 192 + k] : Wr2[n * 192 + (k - 192)];
            wc2[i2] = f2bf(v);
        } else if (idx < 98304 + 73728 + 36864) {    // w1b: 192 x 192
            int i3 = idx - (98304 + 73728);
            w1b[i3] = f2bf(W1[i3]);
        } else {                                     // w2b: 128 x 192
            int i4 = idx - (98304 + 73728 + 36864);
            w2b[i4] = f2bf(W2[i4]);
        }
    }
}

// ---------------------------------------------------------------------------
// CSR build — R11: same proven 3-phase algorithm, both layers batched per
// launch via blockIdx partitioning (17 -> 12 dispatches total).
// ---------------------------------------------------------------------------
__global__ __launch_bounds__(256) void hist_kernel(
    const int* __restrict__ tgt, int* __restrict__ cnt, int E)
{
    int i = blockIdx.x * blockDim.x + threadIdx.x;
    if (i < E) atomicAdd(cnt + tgt[i], 1);
}

// blocks [0,NP1): layer1, [NP1,NP1+NP2): layer2. Same body as proven scan_blocks.
__global__ __launch_bounds__(256) void scan_blocks_both(
    const int* __restrict__ cnt1, int* __restrict__ off1, int* __restrict__ part1,
    const int* __restrict__ cnt2, int* __restrict__ off2, int* __restrict__ part2)
{
    __shared__ int s[256];
    const int b = blockIdx.x;
    const int* cnt; int n; int* off; int* part; int bb;
    if (b < NP1) { cnt = cnt1; n = N_TGT1; off = off1; part = part1; bb = b; }
    else         { cnt = cnt2; n = N_TGT2; off = off2; part = part2; bb = b - NP1; }
    int tid = threadIdx.x;
    int i = bb * 256 + tid;
    int v = (i < n) ? cnt[i] : 0;
    s[tid] = v;
    __syncthreads();
#pragma unroll
    for (int o = 1; o < 256; o <<= 1) {
        int t = (tid >= o) ? s[tid - o] : 0;
        __syncthreads();
        s[tid] += t;
        __syncthreads();
    }
    if (i < n) off[i] = s[tid] - v;
    if (tid == 255) part[bb] = s[255];
}

// both partial scans in one block (two sequential 256-wide scans)
__global__ __launch_bounds__(256) void scan_partials_both(
    int* __restrict__ p1, int* __restrict__ tot1,
    int* __restrict__ p2, int* __restrict__ tot2)
{
    __shared__ int s[256];
    int tid = threadIdx.x;
    // segment 1 (np1 = NP1)
    int v = (tid < NP1) ? p1[tid] : 0;
    s[tid] = v;
    __syncthreads();
#pragma unroll
    for (int o = 1; o < 256; o <<= 1) {
        int t = (tid >= o) ? s[tid - o] : 0;
        __syncthreads();
        s[tid] += t;
        __syncthreads();
    }
    if (tid < NP1) p1[tid] = s[tid] - v;
    if (tid == 255) *tot1 = s[255];
    __syncthreads();
    // segment 2 (np2 = NP2)
    int v2 = (tid < NP2) ? p2[tid] : 0;
    s[tid] = v2;
    __syncthreads();
#pragma unroll
    for (int o = 1; o < 256; o <<= 1) {
        int t = (tid >= o) ? s[tid - o] : 0;
        __syncthreads();
        s[tid] += t;
        __syncthreads();
    }
    if (tid < NP2) p2[tid] = s[tid] - v2;
    if (tid == 255) *tot2 = s[255];
}

__global__ __launch_bounds__(256) void add_off_both(
    int* __restrict__ off1, const int* __restrict__ part1, int* __restrict__ cur1,
    int* __restrict__ off2, const int* __restrict__ part2, int* __restrict__ cur2)
{
    const int b = blockIdx.x;
    int* off; const int* part; int* cur; int n; int bb;
    if (b < NP1) { off = off1; part = part1; cur = cur1; n = N_TGT1; bb = b; }
    else         { off = off2; part = part2; cur = cur2; n = N_TGT2; bb = b - NP1; }
    int i = bb * 256 + threadIdx.x;
    if (i < n) {
        int v = off[i] + part[i >> 8];
        off[i] = v;
        cur[i] = v;
    }
}

// blocks [0,HB1): layer1 edges, [HB1,HB1+HB2): layer2 edges
__global__ __launch_bounds__(256) void fill_both(
    const int* __restrict__ src1, const int* __restrict__ tgt1,
    int* __restrict__ cur1, int* __restrict__ esrc1,
    const int* __restrict__ src2, const int* __restrict__ tgt2,
    int* __restrict__ cur2, int* __restrict__ esrc2)
{
    const int b = blockIdx.x;
    if (b < HB1) {
        int i = b * 256 + threadIdx.x;
        if (i < E1_N) {
            int pos = atomicAdd(cur1 + tgt1[i], 1);
            esrc1[pos] = src1[i];
        }
    } else {
        int i = (b - HB1) * 256 + threadIdx.x;
        if (i < E2_N) {
            int pos = atomicAdd(cur2 + tgt2[i], 1);
            esrc2[pos] = src2[i];
        }
    }
}

// ---------------------------------------------------------------------------
// bf16 CSR aggregation, wave per node. (ILP-8 kept: neutral per R9, harmless)
// ---------------------------------------------------------------------------
__global__ __launch_bounds__(256) void aggregate_bf16_256(
    const int* __restrict__ esrc, const int* __restrict__ off,
    const ushort* __restrict__ X, ushort* __restrict__ seg, int n)
{
    int wid  = blockIdx.x * 4 + (threadIdx.x >> 6);
    int lane = threadIdx.x & 63;
    if (wid >= n) return;
    int s0 = off[wid], s1 = off[wid + 1];
    float a0 = 0, a1 = 0, a2 = 0, a3 = 0;
    const uint2* base = (const uint2*)X;
    int e = s0;
    for (; e + 8 <= s1; e += 8) {
        uint2 v[8];
#pragma unroll
        for (int j = 0; j < 8; ++j)
            v[j] = base[(size_t)esrc[e + j] * 64 + lane];
#pragma unroll
        for (int j = 0; j < 8; ++j) {
            a0 += bf2f((ushort)(v[j].x & 0xffff));
            a1 += bf2f((ushort)(v[j].x >> 16));
            a2 += bf2f((ushort)(v[j].y & 0xffff));
            a3 += bf2f((ushort)(v[j].y >> 16));
        }
    }
    for (; e < s1; ++e) {
        uint2 v = base[(size_t)esrc[e] * 64 + lane];
        a0 += bf2f((ushort)(v.x & 0xffff)); a1 += bf2f((ushort)(v.x >> 16));
        a2 += bf2f((ushort)(v.y & 0xffff)); a3 += bf2f((ushort)(v.y >> 16));
    }
    float inv = (s1 > s0) ? 1.0f / (float)(s1 - s0) : 0.0f;
    uint2 o;
    o.x = pack2(a0 * inv, a1 * inv);
    o.y = pack2(a2 * inv, a3 * inv);
    ((uint2*)seg)[(size_t)wid * 64 + lane] = o;
}

__global__ __launch_bounds__(256) void aggregate_bf16_192(
    const int* __restrict__ esrc, const int* __restrict__ off,
    const ushort* __restrict__ X, ushort* __restrict__ seg, int n)
{
    int wid  = blockIdx.x * 4 + (threadIdx.x >> 6);
    int lane = threadIdx.x & 63;
    if (wid >= n) return;
    int s0 = off[wid], s1 = off[wid + 1];
    float a0 = 0, a1 = 0, a2 = 0, a3 = 0;
    const uint* base = (const uint*)X;
    int e = s0;
    for (; e + 4 <= s1; e += 4) {
        const uint* r0 = base + (size_t)esrc[e] * 96;
        const uint* r1 = base + (size_t)esrc[e + 1] * 96;
        const uint* r2 = base + (size_t)esrc[e + 2] * 96;
        const uint* r3 = base + (size_t)esrc[e + 3] * 96;
        uint w0 = r0[lane], w1 = r1[lane], w2 = r2[lane], w3 = r3[lane];
        a0 += bf2f((ushort)(w0 & 0xffff)) + bf2f((ushort)(w1 & 0xffff))
            + bf2f((ushort)(w2 & 0xffff)) + bf2f((ushort)(w3 & 0xffff));
        a1 += bf2f((ushort)(w0 >> 16)) + bf2f((ushort)(w1 >> 16))
            + bf2f((ushort)(w2 >> 16)) + bf2f((ushort)(w3 >> 16));
        if (lane < 32) {
            uint u0 = r0[64 + lane], u1 = r1[64 + lane],
                 u2 = r2[64 + lane], u3 = r3[64 + lane];
            a2 += bf2f((ushort)(u0 & 0xffff)) + bf2f((ushort)(u1 & 0xffff))
                + bf2f((ushort)(u2 & 0xffff)) + bf2f((ushort)(u3 & 0xffff));
            a3 += bf2f((ushort)(u0 >> 16)) + bf2f((ushort)(u1 >> 16))
                + bf2f((ushort)(u2 >> 16)) + bf2f((ushort)(u3 >> 16));
        }
    }
    for (; e < s1; ++e) {
        const uint* r = base + (size_t)esrc[e] * 96;
        uint v0 = r[lane];
        a0 += bf2f((ushort)(v0 & 0xffff)); a1 += bf2f((ushort)(v0 >> 16));
        if (lane < 32) {
            uint v1 = r[64 + lane];
            a2 += bf2f((ushort)(v1 & 0xffff)); a3 += bf2f((ushort)(v1 >> 16));
        }
    }
    float inv = (s1 > s0) ? 1.0f / (float)(s1 - s0) : 0.0f;
    uint* o = (uint*)seg + (size_t)wid * 96;
    o[lane] = pack2(a0 * inv, a1 * inv);
    if (lane < 32) o[64 + lane] = pack2(a2 * inv, a3 * inv);
}

// ---------------------------------------------------------------------------
// MFMA bf16 GEMM (layer-1 only). <64,192,2,4>: 782 blocks, 3.05/CU (R10 win)
// ---------------------------------------------------------------------------
template <int BM, int BN, int WM, int WN>
__global__ __launch_bounds__(WM * WN * 64) void gemm_mfma(
    const ushort* __restrict__ A1, int K1,
    const ushort* __restrict__ A2, int K2,
    const ushort* __restrict__ W, const float* __restrict__ bias,
    ushort* __restrict__ Cb, float* __restrict__ Cf,
    int M, int relu)
{
    constexpr int TPB = WM * WN * 64;
    constexpr int WTM = BM / WM, WTN = BN / WN;
    constexpr int MF = WTM / 16, NF = WTN / 16;
    constexpr int ROW = 40;
    __shared__ __attribute__((aligned(16))) ushort As[BM * ROW];
    __shared__ __attribute__((aligned(16))) ushort Ws[BN * ROW];
    const int tid  = threadIdx.x;
    const int lane = tid & 63;
    const int wid  = tid >> 6;
    const int wm = wid / WN, wn = wid % WN;
    const int bm = blockIdx.x * BM;
    const int K = K1 + K2;

    f32x4 acc[MF][NF];
#pragma unroll
    for (int i = 0; i < MF; ++i)
#pragma unroll
        for (int j = 0; j < NF; ++j) acc[i][j] = {0.f, 0.f, 0.f, 0.f};

    for (int k0 = 0; k0 < K; k0 += 32) {
#pragma unroll
        for (int c = tid; c < BM * 4; c += TPB) {
            int row = c >> 2, k8 = (c & 3) * 8;
            int m = bm + row, k = k0 + k8;
            uint4 v = make_uint4(0, 0, 0, 0);
            if (m < M) {
                const ushort* s = (k < K1) ? (A1 + (size_t)m * K1 + k)
                                           : (A2 + (size_t)m * K2 + (k - K1));
                v = *(const uint4*)s;
            }
            *(uint4*)&As[row * ROW + k8] = v;
        }
#pragma unroll
        for (int c = tid; c < BN * 4; c += TPB) {
            int row = c >> 2, k8 = (c & 3) * 8;
            uint4 v = *(const uint4*)(W + (size_t)row * K + k0 + k8);
            *(uint4*)&Ws[row * ROW + k8] = v;
        }
        __syncthreads();
        short8 a[MF], b[NF];
#pragma unroll
        for (int mf = 0; mf < MF; ++mf)
            a[mf] = *(const short8*)&As[(wm * WTM + mf * 16 + (lane & 15)) * ROW + (lane >> 4) * 8];
#pragma unroll
        for (int nf = 0; nf < NF; ++nf)
            b[nf] = *(const short8*)&Ws[(wn * WTN + nf * 16 + (lane & 15)) * ROW + (lane >> 4) * 8];
#pragma unroll
        for (int mf = 0; mf < MF; ++mf)
#pragma unroll
            for (int nf = 0; nf < NF; ++nf)
                acc[mf][nf] = __builtin_amdgcn_mfma_f32_16x16x32_bf16(
                    a[mf], b[nf], acc[mf][nf], 0, 0, 0);
        __syncthreads();
    }

#pragma unroll
    for (int mf = 0; mf < MF; ++mf) {
        int r0 = bm + wm * WTM + mf * 16 + (lane >> 4) * 4;
#pragma unroll
        for (int nf = 0; nf < NF; ++nf) {
            int cc = wn * WTN + nf * 16 + (lane & 15);
            float bi = bias[cc];
#pragma unroll
            for (int r = 0; r < 4; ++r) {
                int m = r0 + r;
                if (m >= M) continue;
                float v = acc[mf][nf][r] + bi;
                if (Cf) Cf[(size_t)m * BN + cc] = v;
                if (Cb) Cb[(size_t)m * BN + cc] = f2bf(relu ? fmaxf(v, 0.f) : v);
            }
        }
    }
}

// ---------------------------------------------------------------------------
// tail_fused (R7-proven): h2 = relu([seg2|h1]@wc2^T+bl2); emb = h2@W1^T+b1;
// h3 = relu(emb); logits = h3@W2^T+b2; out_ls = log_softmax(logits).
// ---------------------------------------------------------------------------
__global__ __launch_bounds__(512) void tail_fused(
    const ushort* __restrict__ seg2, const ushort* __restrict__ h1,
    const ushort* __restrict__ wc2, const float* __restrict__ bl2,
    const ushort* __restrict__ w1b, const float* __restrict__ b1,
    const ushort* __restrict__ w2b, const float* __restrict__ b2,
    float* __restrict__ out_emb, float* __restrict__ out_ls, int M)
{
    __shared__ __attribute__((aligned(16))) char lds[122880];
    ushort* As0   = (ushort*)lds;            // [64][40]   5120 B
    ushort* Ws0   = (ushort*)(lds + 5120);   // [192][40]  15360 B
    ushort* h2buf = (ushort*)(lds + 20480);  // [64][200]  25600 B
    ushort* h3buf = (ushort*)(lds + 46080);  // [64][200]  25600 B
    ushort* w2buf = (ushort*)(lds + 71680);  // [128][200] 51200 B
    float*  lsbuf = (float*)(lds + 71680);   // [64][128]  alias after stage B

    const int tid = threadIdx.x, lane = tid & 63, wid = tid >> 6;
    const int wm = wid >> 1, wn = wid & 1;   // 4 x 2 wave grid
    const int bm = blockIdx.x * 64;

    for (int c = tid; c < 128 * 24; c += 512) {
        int r = c / 24, k8 = (c % 24) * 8;
        uint4 v = *(const uint4*)(w2b + r * 192 + k8);
        *(uint4*)&w2buf[r * 200 + k8] = v;
    }

    // ---- stage 0: h2 = relu([seg2 | h1_tgt] @ wc2^T + bl2), K=384 ----
    {
        f32x4 acc[6];
#pragma unroll
        for (int j = 0; j < 6; ++j) acc[j] = {0.f, 0.f, 0.f, 0.f};
        for (int k0 = 0; k0 < 384; k0 += 32) {
            if (tid < 256) {
                int row = tid >> 2, k8 = (tid & 3) * 8;
                int m = bm + row, k = k0 + k8;
                uint4 v = make_uint4(0, 0, 0, 0);
                if (m < M) {
                    const ushort* s = (k < 192) ? (seg2 + (size_t)m * 192 + k)
                                                : (h1 + (size_t)m * 192 + (k - 192));
                    v = *(const uint4*)s;
                }
                *(uint4*)&As0[row * 40 + k8] = v;
            }
            for (int c = tid; c < 768; c += 512) {
                int row = c >> 2, k8 = (c & 3) * 8;
                uint4 v = *(const uint4*)(wc2 + (size_t)row * 384 + k0 + k8);
                *(uint4*)&Ws0[row * 40 + k8] = v;
            }
            __syncthreads();
            short8 a = *(const short8*)&As0[(wm * 16 + (lane & 15)) * 40 + (lane >> 4) * 8];
#pragma unroll
            for (int nf = 0; nf < 6; ++nf) {
                short8 b = *(const short8*)&Ws0[(wn * 96 + nf * 16 + (lane & 15)) * 40 + (lane >> 4) * 8];
                acc[nf] = __builtin_amdgcn_mfma_f32_16x16x32_bf16(a, b, acc[nf], 0, 0, 0);
            }
            __syncthreads();
        }
#pragma unroll
        for (int nf = 0; nf < 6; ++nf) {
            int cc = wn * 96 + nf * 16 + (lane & 15);
            float bi = bl2[cc];
#pragma unroll
            for (int r = 0; r < 4; ++r) {
                int row = wm * 16 + (lane >> 4) * 4 + r;
                h2buf[row * 200 + cc] = f2bf(fmaxf(acc[nf][r] + bi, 0.f));
            }
        }
    }
    __syncthreads();

    // ---- stage A: emb = h2 @ W1^T + b1 (f32 out); h3 = relu -> LDS ----
    {
        f32x4 acc[6];
#pragma unroll
        for (int j = 0; j < 6; ++j) acc[j] = {0.f, 0.f, 0.f, 0.f};
        for (int k0 = 0; k0 < 192; k0 += 32) {
            for (int c = tid; c < 768; c += 512) {
                int row = c >> 2, k8 = (c & 3) * 8;
                uint4 v = *(const uint4*)(w1b + (size_t)row * 192 + k0 + k8);
                *(uint4*)&Ws0[row * 40 + k8] = v;
            }
            __syncthreads();
            short8 a = *(const short8*)&h2buf[(wm * 16 + (lane & 15)) * 200 + k0 + (lane >> 4) * 8];
#pragma unroll
            for (int nf = 0; nf < 6; ++nf) {
                short8 b = *(const short8*)&Ws0[(wn * 96 + nf * 16 + (lane & 15)) * 40 + (lane >> 4) * 8];
                acc[nf] = __builtin_amdgcn_mfma_f32_16x16x32_bf16(a, b, acc[nf], 0, 0, 0);
            }
            __syncthreads();
        }
#pragma unroll
        for (int nf = 0; nf < 6; ++nf) {
            int cc = wn * 96 + nf * 16 + (lane & 15);
            float bi = b1[cc];
#pragma unroll
            for (int r = 0; r < 4; ++r) {
                int row = wm * 16 + (lane >> 4) * 4 + r;
                int m = bm + row;
                float v = acc[nf][r] + bi;
                if (m < M) out_emb[(size_t)m * 192 + cc] = v;
                h3buf[row * 200 + cc] = f2bf(fmaxf(v, 0.f));
            }
        }
    }
    __syncthreads();

    // ---- stage B: logits = h3 @ W2^T + b2 (all operands in LDS) ----
    {
        f32x4 acc[4];
#pragma unroll
        for (int j = 0; j < 4; ++j) acc[j] = {0.f, 0.f, 0.f, 0.f};
#pragma unroll
        for (int k0 = 0; k0 < 192; k0 += 32) {
            short8 a = *(const short8*)&h3buf[(wm * 16 + (lane & 15)) * 200 + k0 + (lane >> 4) * 8];
#pragma unroll
            for (int nf = 0; nf < 4; ++nf) {
                short8 b = *(const short8*)&w2buf[(wn * 64 + nf * 16 + (lane & 15)) * 200 + k0 + (lane >> 4) * 8];
                acc[nf] = __builtin_amdgcn_mfma_f32_16x16x32_bf16(a, b, acc[nf], 0, 0, 0);
            }
        }
        __syncthreads();
#pragma unroll
        for (int nf = 0; nf < 4; ++nf) {
            int cc = wn * 64 + nf * 16 + (lane & 15);
            float bi = b2[cc];
#pragma unroll
            for (int r = 0; r < 4; ++r) {
                int row = wm * 16 + (lane >> 4) * 4 + r;
                lsbuf[row * 128 + cc] = acc[nf][r] + bi;
            }
        }
    }
    __syncthreads();

    for (int i = 0; i < 8; ++i) {
        int row = wid * 8 + i;
        float a = lsbuf[row * 128 + lane], b = lsbuf[row * 128 + 64 + lane];
        float mx = fmaxf(a, b);
#pragma unroll
        for (int o = 32; o > 0; o >>= 1) mx = fmaxf(mx, __shfl_xor(mx, o));
        float s = expf(a - mx) + expf(b - mx);
#pragma unroll
        for (int o = 32; o > 0; o >>= 1) s += __shfl_xor(s, o);
        float ls = logf(s) + mx;
        int m = bm + row;
        if (m < M) {
            out_ls[(size_t)m * 128 + lane]      = a - ls;
            out_ls[(size_t)m * 128 + lane + 64] = b - ls;
        }
    }
}

// ---------------------------------------------------------------------------
extern "C" void kernel_launch(void* const* d_in, const int* in_sizes, int n_in,
                              void* d_out, int out_size, void* d_ws, size_t ws_size,
                              hipStream_t stream)
{
    const float* x   = (const float*)d_in[0];
    const int*   ei1 = (const int*)d_in[1];
    const int*   ei2 = (const int*)d_in[2];
    const float* Wl1 = (const float*)d_in[3];
    const float* bl1 = (const float*)d_in[4];
    const float* Wr1 = (const float*)d_in[5];
    const float* Wl2 = (const float*)d_in[6];
    const float* bl2 = (const float*)d_in[7];
    const float* Wr2 = (const float*)d_in[8];
    const float* W1  = (const float*)d_in[9];
    const float* b1  = (const float*)d_in[10];
    const float* W2  = (const float*)d_in[11];
    const float* b2  = (const float*)d_in[12];

    char* ws = (char*)d_ws;
    // ---- layout: esrc2 NO LONGER overlays esrc1 (fill_both writes both
    //      concurrently). Peak ~157.2 MB (= R5's passing peak).
    ushort* xb    = (ushort*)(ws + 0);            // 102,400,000  [200000x256]
    ushort* seg1b = (ushort*)(ws + 102400000);    //  25,600,000  [50000x256]
    ushort* h1b   = (ushort*)(ws + 128000000);    //  19,200,000  [50000x192]
    int*    esrc1 = (int*)   (ws + 147200000);    //   4,000,000
    int*    cnt1  = (int*)   (ws + 151200000);    //     200,000
    int*    cnt2  = (int*)   (ws + 151400000);    //      40,000  (adjacent: 1 memset)
    int*    off1  = (int*)   (ws + 151440000);    //     200,004
    int*    off2  = (int*)   (ws + 151640064);    //      40,004
    int*    part1 = (int*)   (ws + 151680128);    //       1,024
    ushort* wc1   = (ushort*)(ws + 151681152);    //     196,608  [192][512]
    ushort* wc2   = (ushort*)(ws + 151877760);    //     147,456  [192][384]
    ushort* w1b   = (ushort*)(ws + 152025216);    //      73,728  [192][192]
    ushort* w2b   = (ushort*)(ws + 152098944);    //      49,152  [128][192]
    ushort* seg2b = (ushort*)(ws + 152148096);    //   3,840,000  [10000x192]
    int*    esrc2 = (int*)   (ws + 155988096);    //   1,200,000
    int*    part2 = (int*)   (ws + 157188096);    //       1,024

    float* out_ls  = (float*)d_out;                           // [10000,128]
    float* out_emb = (float*)d_out + (size_t)N_TGT2 * F_OUT;  // [10000,192]

    // one memset for both histograms
    hipMemsetAsync(cnt1, 0, 240000, stream);

    // ---- conversions (single launch) ----
    prep<<<2176, 256, 0, stream>>>(
        (const float4*)x, (uint2*)xb, Wl1, Wr1, Wl2, Wr2, W1, W2,
        wc1, wc2, w1b, w2b);

    // ---- both CSR builds, batched per phase (proven 3-phase algorithm) ----
    hist_kernel<<<HB1, 256, 0, stream>>>(ei1 + E1_N, cnt1, E1_N);
    hist_kernel<<<HB2, 256, 0, stream>>>(ei2 + E2_N, cnt2, E2_N);
    scan_blocks_both<<<NP1 + NP2, 256, 0, stream>>>(cnt1, off1, part1, cnt2, off2, part2);
    scan_partials_both<<<1, 256, 0, stream>>>(part1, off1 + N_TGT1, part2, off2 + N_TGT2);
    add_off_both<<<NP1 + NP2, 256, 0, stream>>>(off1, part1, cnt1, off2, part2, cnt2);
    fill_both<<<HB1 + HB2, 256, 0, stream>>>(
        ei1, ei1 + E1_N, cnt1, esrc1, ei2, ei2 + E2_N, cnt2, esrc2);

    // ---- layer 1 ----
    aggregate_bf16_256<<<(N_TGT1 + 3) / 4, 256, 0, stream>>>(esrc1, off1, xb, seg1b, N_TGT1);
    gemm_mfma<64, 192, 2, 4><<<(N_TGT1 + 63) / 64, 512, 0, stream>>>(
        seg1b, F_IN, xb, F_IN, wc1, bl1, h1b, nullptr, N_TGT1, 1);

    // ---- layer 2 ----
    aggregate_bf16_192<<<(N_TGT2 + 3) / 4, 256, 0, stream>>>(esrc2, off2, h1b, seg2b, N_TGT2);

    // fused tail: gemm2 + gemm3(emb) + gemm4(logits) + log_softmax
    tail_fused<<<(N_TGT2 + 63) / 64, 512, 0, stream>>>(
        seg2b, h1b, wc2, bl2, w1b, b1, w2b, b2, out_emb, out_ls, N_TGT2);
}

// Round 12
// 367.867 us; speedup vs baseline: 1.0324x; 1.0324x over previous
//
#include <hip/hip_runtime.h>
#include <hip/hip_bf16.h>

// Problem constants
#define N_SRC1 200000
#define N_TGT1 50000
#define N_TGT2 10000
#define E1_N   1000000
#define E2_N   300000
#define F_IN   256
#define F_HID  192
#define F_OUT  128

typedef __attribute__((ext_vector_type(4))) float f32x4;
typedef __attribute__((ext_vector_type(8))) short short8;

__device__ inline float bf2f(ushort u) {
    union { uint i; float f; } c; c.i = ((uint)u) << 16; return c.f;
}
__device__ inline ushort f2bf(float f) {
    union { float f; uint i; } c; c.f = f;
    uint u = c.i;
    return (ushort)((u + 0x7FFFu + ((u >> 16) & 1u)) >> 16);  // RNE
}
__device__ inline uint pack2(float a, float b) {
    return (uint)f2bf(a) | ((uint)f2bf(b) << 16);
}

#define HB1 3907   // (E1_N+255)/256
#define HB2 1172   // (E2_N+255)/256
#define NP1 196    // (N_TGT1+255)/256
#define NP2 40     // (N_TGT2+255)/256
#define PXB 25000  // x-convert blocks: 200000*256/8 elems / 256 thr = 25000

// ---------------------------------------------------------------------------
// prep — R12: flat exact-sized x-convert (2 float4 -> 1 uint4 per thread,
// no grid-stride loop); weight packs in blocks [PXB, PXB+128).
// ---------------------------------------------------------------------------
__global__ __launch_bounds__(256) void prep(
    const float4* __restrict__ x4, uint4* __restrict__ xb4,
    const float* __restrict__ Wl1, const float* __restrict__ Wr1,
    const float* __restrict__ Wl2, const float* __restrict__ Wr2,
    const float* __restrict__ W1, const float* __restrict__ W2,
    ushort* __restrict__ wc1, ushort* __restrict__ wc2,
    ushort* __restrict__ w1b, ushort* __restrict__ w2b)
{
    const int b = blockIdx.x, tid = threadIdx.x;
    if (b < PXB) {
        size_t j = (size_t)b * 256 + tid;        // uint4 index, 6.4M total
        const float4* s = x4 + 2 * j;
        float4 v0 = s[0], v1 = s[1];
        uint4 o;
        o.x = pack2(v0.x, v0.y);
        o.y = pack2(v0.z, v0.w);
        o.z = pack2(v1.x, v1.y);
        o.w = pack2(v1.z, v1.w);
        xb4[j] = o;
        return;
    }
    const int wt = (b - PXB) * 256 + tid;
    for (int idx = wt; idx < 233472; idx += 128 * 256) {
        if (idx < 98304) {                           // wc1: 192 x 512
            int n = idx >> 9, k = idx & 511;
            float v = (k < 256) ? Wl1[n * 256 + k] : Wr1[n * 256 + (k - 256)];
            wc1[idx] = f2bf(v);
        } else if (idx < 98304 + 73728) {            // wc2: 192 x 384
            int i2 = idx - 98304;
            int n = i2 / 384, k = i2 - n * 384;
            float v = (k < 192) ? Wl2[n * 192 + k] : Wr2[n * 192 + (k - 192)];
            wc2[i2] = f2bf(v);
        } else if (idx < 98304 + 73728 + 36864) {    // w1b: 192 x 192
            int i3 = idx - (98304 + 73728);
            w1b[i3] = f2bf(W1[i3]);
        } else {                                     // w2b: 128 x 192
            int i4 = idx - (98304 + 73728 + 36864);
            w2b[i4] = f2bf(W2[i4]);
        }
    }
}

// ---------------------------------------------------------------------------
// CSR build — R11 batched 3-phase chain (proven algorithm, neutral batching)
// ---------------------------------------------------------------------------
__global__ __launch_bounds__(256) void hist_kernel(
    const int* __restrict__ tgt, int* __restrict__ cnt, int E)
{
    int i = blockIdx.x * blockDim.x + threadIdx.x;
    if (i < E) atomicAdd(cnt + tgt[i], 1);
}

__global__ __launch_bounds__(256) void scan_blocks_both(
    const int* __restrict__ cnt1, int* __restrict__ off1, int* __restrict__ part1,
    const int* __restrict__ cnt2, int* __restrict__ off2, int* __restrict__ part2)
{
    __shared__ int s[256];
    const int b = blockIdx.x;
    const int* cnt; int n; int* off; int* part; int bb;
    if (b < NP1) { cnt = cnt1; n = N_TGT1; off = off1; part = part1; bb = b; }
    else         { cnt = cnt2; n = N_TGT2; off = off2; part = part2; bb = b - NP1; }
    int tid = threadIdx.x;
    int i = bb * 256 + tid;
    int v = (i < n) ? cnt[i] : 0;
    s[tid] = v;
    __syncthreads();
#pragma unroll
    for (int o = 1; o < 256; o <<= 1) {
        int t = (tid >= o) ? s[tid - o] : 0;
        __syncthreads();
        s[tid] += t;
        __syncthreads();
    }
    if (i < n) off[i] = s[tid] - v;
    if (tid == 255) part[bb] = s[255];
}

__global__ __launch_bounds__(256) void scan_partials_both(
    int* __restrict__ p1, int* __restrict__ tot1,
    int* __restrict__ p2, int* __restrict__ tot2)
{
    __shared__ int s[256];
    int tid = threadIdx.x;
    int v = (tid < NP1) ? p1[tid] : 0;
    s[tid] = v;
    __syncthreads();
#pragma unroll
    for (int o = 1; o < 256; o <<= 1) {
        int t = (tid >= o) ? s[tid - o] : 0;
        __syncthreads();
        s[tid] += t;
        __syncthreads();
    }
    if (tid < NP1) p1[tid] = s[tid] - v;
    if (tid == 255) *tot1 = s[255];
    __syncthreads();
    int v2 = (tid < NP2) ? p2[tid] : 0;
    s[tid] = v2;
    __syncthreads();
#pragma unroll
    for (int o = 1; o < 256; o <<= 1) {
        int t = (tid >= o) ? s[tid - o] : 0;
        __syncthreads();
        s[tid] += t;
        __syncthreads();
    }
    if (tid < NP2) p2[tid] = s[tid] - v2;
    if (tid == 255) *tot2 = s[255];
}

__global__ __launch_bounds__(256) void add_off_both(
    int* __restrict__ off1, const int* __restrict__ part1, int* __restrict__ cur1,
    int* __restrict__ off2, const int* __restrict__ part2, int* __restrict__ cur2)
{
    const int b = blockIdx.x;
    int* off; const int* part; int* cur; int n; int bb;
    if (b < NP1) { off = off1; part = part1; cur = cur1; n = N_TGT1; bb = b; }
    else         { off = off2; part = part2; cur = cur2; n = N_TGT2; bb = b - NP1; }
    int i = bb * 256 + threadIdx.x;
    if (i < n) {
        int v = off[i] + part[i >> 8];
        off[i] = v;
        cur[i] = v;
    }
}

__global__ __launch_bounds__(256) void fill_both(
    const int* __restrict__ src1, const int* __restrict__ tgt1,
    int* __restrict__ cur1, int* __restrict__ esrc1,
    const int* __restrict__ src2, const int* __restrict__ tgt2,
    int* __restrict__ cur2, int* __restrict__ esrc2)
{
    const int b = blockIdx.x;
    if (b < HB1) {
        int i = b * 256 + threadIdx.x;
        if (i < E1_N) {
            int pos = atomicAdd(cur1 + tgt1[i], 1);
            esrc1[pos] = src1[i];
        }
    } else {
        int i = (b - HB1) * 256 + threadIdx.x;
        if (i < E2_N) {
            int pos = atomicAdd(cur2 + tgt2[i], 1);
            esrc2[pos] = src2[i];
        }
    }
}

// ---------------------------------------------------------------------------
// bf16 CSR aggregation, wave per node. (ILP-8 kept: neutral per R9, harmless)
// ---------------------------------------------------------------------------
__global__ __launch_bounds__(256) void aggregate_bf16_256(
    const int* __restrict__ esrc, const int* __restrict__ off,
    const ushort* __restrict__ X, ushort* __restrict__ seg, int n)
{
    int wid  = blockIdx.x * 4 + (threadIdx.x >> 6);
    int lane = threadIdx.x & 63;
    if (wid >= n) return;
    int s0 = off[wid], s1 = off[wid + 1];
    float a0 = 0, a1 = 0, a2 = 0, a3 = 0;
    const uint2* base = (const uint2*)X;
    int e = s0;
    for (; e + 8 <= s1; e += 8) {
        uint2 v[8];
#pragma unroll
        for (int j = 0; j < 8; ++j)
            v[j] = base[(size_t)esrc[e + j] * 64 + lane];
#pragma unroll
        for (int j = 0; j < 8; ++j) {
            a0 += bf2f((ushort)(v[j].x & 0xffff));
            a1 += bf2f((ushort)(v[j].x >> 16));
            a2 += bf2f((ushort)(v[j].y & 0xffff));
            a3 += bf2f((ushort)(v[j].y >> 16));
        }
    }
    for (; e < s1; ++e) {
        uint2 v = base[(size_t)esrc[e] * 64 + lane];
        a0 += bf2f((ushort)(v.x & 0xffff)); a1 += bf2f((ushort)(v.x >> 16));
        a2 += bf2f((ushort)(v.y & 0xffff)); a3 += bf2f((ushort)(v.y >> 16));
    }
    float inv = (s1 > s0) ? 1.0f / (float)(s1 - s0) : 0.0f;
    uint2 o;
    o.x = pack2(a0 * inv, a1 * inv);
    o.y = pack2(a2 * inv, a3 * inv);
    ((uint2*)seg)[(size_t)wid * 64 + lane] = o;
}

__global__ __launch_bounds__(256) void aggregate_bf16_192(
    const int* __restrict__ esrc, const int* __restrict__ off,
    const ushort* __restrict__ X, ushort* __restrict__ seg, int n)
{
    int wid  = blockIdx.x * 4 + (threadIdx.x >> 6);
    int lane = threadIdx.x & 63;
    if (wid >= n) return;
    int s0 = off[wid], s1 = off[wid + 1];
    float a0 = 0, a1 = 0, a2 = 0, a3 = 0;
    const uint* base = (const uint*)X;
    int e = s0;
    for (; e + 4 <= s1; e += 4) {
        const uint* r0 = base + (size_t)esrc[e] * 96;
        const uint* r1 = base + (size_t)esrc[e + 1] * 96;
        const uint* r2 = base + (size_t)esrc[e + 2] * 96;
        const uint* r3 = base + (size_t)esrc[e + 3] * 96;
        uint w0 = r0[lane], w1 = r1[lane], w2 = r2[lane], w3 = r3[lane];
        a0 += bf2f((ushort)(w0 & 0xffff)) + bf2f((ushort)(w1 & 0xffff))
            + bf2f((ushort)(w2 & 0xffff)) + bf2f((ushort)(w3 & 0xffff));
        a1 += bf2f((ushort)(w0 >> 16)) + bf2f((ushort)(w1 >> 16))
            + bf2f((ushort)(w2 >> 16)) + bf2f((ushort)(w3 >> 16));
        if (lane < 32) {
            uint u0 = r0[64 + lane], u1 = r1[64 + lane],
                 u2 = r2[64 + lane], u3 = r3[64 + lane];
            a2 += bf2f((ushort)(u0 & 0xffff)) + bf2f((ushort)(u1 & 0xffff))
                + bf2f((ushort)(u2 & 0xffff)) + bf2f((ushort)(u3 & 0xffff));
            a3 += bf2f((ushort)(u0 >> 16)) + bf2f((ushort)(u1 >> 16))
                + bf2f((ushort)(u2 >> 16)) + bf2f((ushort)(u3 >> 16));
        }
    }
    for (; e < s1; ++e) {
        const uint* r = base + (size_t)esrc[e] * 96;
        uint v0 = r[lane];
        a0 += bf2f((ushort)(v0 & 0xffff)); a1 += bf2f((ushort)(v0 >> 16));
        if (lane < 32) {
            uint v1 = r[64 + lane];
            a2 += bf2f((ushort)(v1 & 0xffff)); a3 += bf2f((ushort)(v1 >> 16));
        }
    }
    float inv = (s1 > s0) ? 1.0f / (float)(s1 - s0) : 0.0f;
    uint* o = (uint*)seg + (size_t)wid * 96;
    o[lane] = pack2(a0 * inv, a1 * inv);
    if (lane < 32) o[64 + lane] = pack2(a2 * inv, a3 * inv);
}

// ---------------------------------------------------------------------------
// MFMA bf16 GEMM (layer-1 only). <64,192,2,4>: 782 blocks, 3.05/CU (R10 win)
// ---------------------------------------------------------------------------
template <int BM, int BN, int WM, int WN>
__global__ __launch_bounds__(WM * WN * 64) void gemm_mfma(
    const ushort* __restrict__ A1, int K1,
    const ushort* __restrict__ A2, int K2,
    const ushort* __restrict__ W, const float* __restrict__ bias,
    ushort* __restrict__ Cb, float* __restrict__ Cf,
    int M, int relu)
{
    constexpr int TPB = WM * WN * 64;
    constexpr int WTM = BM / WM, WTN = BN / WN;
    constexpr int MF = WTM / 16, NF = WTN / 16;
    constexpr int ROW = 40;
    __shared__ __attribute__((aligned(16))) ushort As[BM * ROW];
    __shared__ __attribute__((aligned(16))) ushort Ws[BN * ROW];
    const int tid  = threadIdx.x;
    const int lane = tid & 63;
    const int wid  = tid >> 6;
    const int wm = wid / WN, wn = wid % WN;
    const int bm = blockIdx.x * BM;
    const int K = K1 + K2;

    f32x4 acc[MF][NF];
#pragma unroll
    for (int i = 0; i < MF; ++i)
#pragma unroll
        for (int j = 0; j < NF; ++j) acc[i][j] = {0.f, 0.f, 0.f, 0.f};

    for (int k0 = 0; k0 < K; k0 += 32) {
#pragma unroll
        for (int c = tid; c < BM * 4; c += TPB) {
            int row = c >> 2, k8 = (c & 3) * 8;
            int m = bm + row, k = k0 + k8;
            uint4 v = make_uint4(0, 0, 0, 0);
            if (m < M) {
                const ushort* s = (k < K1) ? (A1 + (size_t)m * K1 + k)
                                           : (A2 + (size_t)m * K2 + (k - K1));
                v = *(const uint4*)s;
            }
            *(uint4*)&As[row * ROW + k8] = v;
        }
#pragma unroll
        for (int c = tid; c < BN * 4; c += TPB) {
            int row = c >> 2, k8 = (c & 3) * 8;
            uint4 v = *(const uint4*)(W + (size_t)row * K + k0 + k8);
            *(uint4*)&Ws[row * ROW + k8] = v;
        }
        __syncthreads();
        short8 a[MF], b[NF];
#pragma unroll
        for (int mf = 0; mf < MF; ++mf)
            a[mf] = *(const short8*)&As[(wm * WTM + mf * 16 + (lane & 15)) * ROW + (lane >> 4) * 8];
#pragma unroll
        for (int nf = 0; nf < NF; ++nf)
            b[nf] = *(const short8*)&Ws[(wn * WTN + nf * 16 + (lane & 15)) * ROW + (lane >> 4) * 8];
#pragma unroll
        for (int mf = 0; mf < MF; ++mf)
#pragma unroll
            for (int nf = 0; nf < NF; ++nf)
                acc[mf][nf] = __builtin_amdgcn_mfma_f32_16x16x32_bf16(
                    a[mf], b[nf], acc[mf][nf], 0, 0, 0);
        __syncthreads();
    }

#pragma unroll
    for (int mf = 0; mf < MF; ++mf) {
        int r0 = bm + wm * WTM + mf * 16 + (lane >> 4) * 4;
#pragma unroll
        for (int nf = 0; nf < NF; ++nf) {
            int cc = wn * WTN + nf * 16 + (lane & 15);
            float bi = bias[cc];
#pragma unroll
            for (int r = 0; r < 4; ++r) {
                int m = r0 + r;
                if (m >= M) continue;
                float v = acc[mf][nf][r] + bi;
                if (Cf) Cf[(size_t)m * BN + cc] = v;
                if (Cb) Cb[(size_t)m * BN + cc] = f2bf(relu ? fmaxf(v, 0.f) : v);
            }
        }
    }
}

// ---------------------------------------------------------------------------
// tail_fused (R7-proven): h2 = relu([seg2|h1]@wc2^T+bl2); emb = h2@W1^T+b1;
// h3 = relu(emb); logits = h3@W2^T+b2; out_ls = log_softmax(logits).
// ---------------------------------------------------------------------------
__global__ __launch_bounds__(512) void tail_fused(
    const ushort* __restrict__ seg2, const ushort* __restrict__ h1,
    const ushort* __restrict__ wc2, const float* __restrict__ bl2,
    const ushort* __restrict__ w1b, const float* __restrict__ b1,
    const ushort* __restrict__ w2b, const float* __restrict__ b2,
    float* __restrict__ out_emb, float* __restrict__ out_ls, int M)
{
    __shared__ __attribute__((aligned(16))) char lds[122880];
    ushort* As0   = (ushort*)lds;            // [64][40]   5120 B
    ushort* Ws0   = (ushort*)(lds + 5120);   // [192][40]  15360 B
    ushort* h2buf = (ushort*)(lds + 20480);  // [64][200]  25600 B
    ushort* h3buf = (ushort*)(lds + 46080);  // [64][200]  25600 B
    ushort* w2buf = (ushort*)(lds + 71680);  // [128][200] 51200 B
    float*  lsbuf = (float*)(lds + 71680);   // [64][128]  alias after stage B

    const int tid = threadIdx.x, lane = tid & 63, wid = tid >> 6;
    const int wm = wid >> 1, wn = wid & 1;   // 4 x 2 wave grid
    const int bm = blockIdx.x * 64;

    for (int c = tid; c < 128 * 24; c += 512) {
        int r = c / 24, k8 = (c % 24) * 8;
        uint4 v = *(const uint4*)(w2b + r * 192 + k8);
        *(uint4*)&w2buf[r * 200 + k8] = v;
    }

    // ---- stage 0: h2 = relu([seg2 | h1_tgt] @ wc2^T + bl2), K=384 ----
    {
        f32x4 acc[6];
#pragma unroll
        for (int j = 0; j < 6; ++j) acc[j] = {0.f, 0.f, 0.f, 0.f};
        for (int k0 = 0; k0 < 384; k0 += 32) {
            if (tid < 256) {
                int row = tid >> 2, k8 = (tid & 3) * 8;
                int m = bm + row, k = k0 + k8;
                uint4 v = make_uint4(0, 0, 0, 0);
                if (m < M) {
                    const ushort* s = (k < 192) ? (seg2 + (size_t)m * 192 + k)
                                                : (h1 + (size_t)m * 192 + (k - 192));
                    v = *(const uint4*)s;
                }
                *(uint4*)&As0[row * 40 + k8] = v;
            }
            for (int c = tid; c < 768; c += 512) {
                int row = c >> 2, k8 = (c & 3) * 8;
                uint4 v = *(const uint4*)(wc2 + (size_t)row * 384 + k0 + k8);
                *(uint4*)&Ws0[row * 40 + k8] = v;
            }
            __syncthreads();
            short8 a = *(const short8*)&As0[(wm * 16 + (lane & 15)) * 40 + (lane >> 4) * 8];
#pragma unroll
            for (int nf = 0; nf < 6; ++nf) {
                short8 b = *(const short8*)&Ws0[(wn * 96 + nf * 16 + (lane & 15)) * 40 + (lane >> 4) * 8];
                acc[nf] = __builtin_amdgcn_mfma_f32_16x16x32_bf16(a, b, acc[nf], 0, 0, 0);
            }
            __syncthreads();
        }
#pragma unroll
        for (int nf = 0; nf < 6; ++nf) {
            int cc = wn * 96 + nf * 16 + (lane & 15);
            float bi = bl2[cc];
#pragma unroll
            for (int r = 0; r < 4; ++r) {
                int row = wm * 16 + (lane >> 4) * 4 + r;
                h2buf[row * 200 + cc] = f2bf(fmaxf(acc[nf][r] + bi, 0.f));
            }
        }
    }
    __syncthreads();

    // ---- stage A: emb = h2 @ W1^T + b1 (f32 out); h3 = relu -> LDS ----
    {
        f32x4 acc[6];
#pragma unroll
        for (int j = 0; j < 6; ++j) acc[j] = {0.f, 0.f, 0.f, 0.f};
        for (int k0 = 0; k0 < 192; k0 += 32) {
            for (int c = tid; c < 768; c += 512) {
                int row = c >> 2, k8 = (c & 3) * 8;
                uint4 v = *(const uint4*)(w1b + (size_t)row * 192 + k0 + k8);
                *(uint4*)&Ws0[row * 40 + k8] = v;
            }
            __syncthreads();
            short8 a = *(const short8*)&h2buf[(wm * 16 + (lane & 15)) * 200 + k0 + (lane >> 4) * 8];
#pragma unroll
            for (int nf = 0; nf < 6; ++nf) {
                short8 b = *(const short8*)&Ws0[(wn * 96 + nf * 16 + (lane & 15)) * 40 + (lane >> 4) * 8];
                acc[nf] = __builtin_amdgcn_mfma_f32_16x16x32_bf16(a, b, acc[nf], 0, 0, 0);
            }
            __syncthreads();
        }
#pragma unroll
        for (int nf = 0; nf < 6; ++nf) {
            int cc = wn * 96 + nf * 16 + (lane & 15);
            float bi = b1[cc];
#pragma unroll
            for (int r = 0; r < 4; ++r) {
                int row = wm * 16 + (lane >> 4) * 4 + r;
                int m = bm + row;
                float v = acc[nf][r] + bi;
                if (m < M) out_emb[(size_t)m * 192 + cc] = v;
                h3buf[row * 200 + cc] = f2bf(fmaxf(v, 0.f));
            }
        }
    }
    __syncthreads();

    // ---- stage B: logits = h3 @ W2^T + b2 (all operands in LDS) ----
    {
        f32x4 acc[4];
#pragma unroll
        for (int j = 0; j < 4; ++j) acc[j] = {0.f, 0.f, 0.f, 0.f};
#pragma unroll
        for (int k0 = 0; k0 < 192; k0 += 32) {
            short8 a = *(const short8*)&h3buf[(wm * 16 + (lane & 15)) * 200 + k0 + (lane >> 4) * 8];
#pragma unroll
            for (int nf = 0; nf < 4; ++nf) {
                short8 b = *(const short8*)&w2buf[(wn * 64 + nf * 16 + (lane & 15)) * 200 + k0 + (lane >> 4) * 8];
                acc[nf] = __builtin_amdgcn_mfma_f32_16x16x32_bf16(a, b, acc[nf], 0, 0, 0);
            }
        }
        __syncthreads();
#pragma unroll
        for (int nf = 0; nf < 4; ++nf) {
            int cc = wn * 64 + nf * 16 + (lane & 15);
            float bi = b2[cc];
#pragma unroll
            for (int r = 0; r < 4; ++r) {
                int row = wm * 16 + (lane >> 4) * 4 + r;
                lsbuf[row * 128 + cc] = acc[nf][r] + bi;
            }
        }
    }
    __syncthreads();

    for (int i = 0; i < 8; ++i) {
        int row = wid * 8 + i;
        float a = lsbuf[row * 128 + lane], b = lsbuf[row * 128 + 64 + lane];
        float mx = fmaxf(a, b);
#pragma unroll
        for (int o = 32; o > 0; o >>= 1) mx = fmaxf(mx, __shfl_xor(mx, o));
        float s = expf(a - mx) + expf(b - mx);
#pragma unroll
        for (int o = 32; o > 0; o >>= 1) s += __shfl_xor(s, o);
        float ls = logf(s) + mx;
        int m = bm + row;
        if (m < M) {
            out_ls[(size_t)m * 128 + lane]      = a - ls;
            out_ls[(size_t)m * 128 + lane + 64] = b - ls;
        }
    }
}

// ---------------------------------------------------------------------------
extern "C" void kernel_launch(void* const* d_in, const int* in_sizes, int n_in,
                              void* d_out, int out_size, void* d_ws, size_t ws_size,
                              hipStream_t stream)
{
    const float* x   = (const float*)d_in[0];
    const int*   ei1 = (const int*)d_in[1];
    const int*   ei2 = (const int*)d_in[2];
    const float* Wl1 = (const float*)d_in[3];
    const float* bl1 = (const float*)d_in[4];
    const float* Wr1 = (const float*)d_in[5];
    const float* Wl2 = (const float*)d_in[6];
    const float* bl2 = (const float*)d_in[7];
    const float* Wr2 = (const float*)d_in[8];
    const float* W1  = (const float*)d_in[9];
    const float* b1  = (const float*)d_in[10];
    const float* W2  = (const float*)d_in[11];
    const float* b2  = (const float*)d_in[12];

    char* ws = (char*)d_ws;
    // ---- layout (R11) ----
    ushort* xb    = (ushort*)(ws + 0);            // 102,400,000  [200000x256]
    ushort* seg1b = (ushort*)(ws + 102400000);    //  25,600,000  [50000x256]
    ushort* h1b   = (ushort*)(ws + 128000000);    //  19,200,000  [50000x192]
    int*    esrc1 = (int*)   (ws + 147200000);    //   4,000,000
    int*    cnt1  = (int*)   (ws + 151200000);    //     200,000
    int*    cnt2  = (int*)   (ws + 151400000);    //      40,000  (adjacent: 1 memset)
    int*    off1  = (int*)   (ws + 151440000);    //     200,004
    int*    off2  = (int*)   (ws + 151640064);    //      40,004
    int*    part1 = (int*)   (ws + 151680128);    //       1,024
    ushort* wc1   = (ushort*)(ws + 151681152);    //     196,608  [192][512]
    ushort* wc2   = (ushort*)(ws + 151877760);    //     147,456  [192][384]
    ushort* w1b   = (ushort*)(ws + 152025216);    //      73,728  [192][192]
    ushort* w2b   = (ushort*)(ws + 152098944);    //      49,152  [128][192]
    ushort* seg2b = (ushort*)(ws + 152148096);    //   3,840,000  [10000x192]
    int*    esrc2 = (int*)   (ws + 155988096);    //   1,200,000
    int*    part2 = (int*)   (ws + 157188096);    //       1,024

    float* out_ls  = (float*)d_out;                           // [10000,128]
    float* out_emb = (float*)d_out + (size_t)N_TGT2 * F_OUT;  // [10000,192]

    // one memset for both histograms
    hipMemsetAsync(cnt1, 0, 240000, stream);

    // ---- conversions: R12 flat x-convert + weight packs ----
    prep<<<PXB + 128, 256, 0, stream>>>(
        (const float4*)x, (uint4*)xb, Wl1, Wr1, Wl2, Wr2, W1, W2,
        wc1, wc2, w1b, w2b);

    // ---- both CSR builds, batched per phase (proven 3-phase algorithm) ----
    hist_kernel<<<HB1, 256, 0, stream>>>(ei1 + E1_N, cnt1, E1_N);
    hist_kernel<<<HB2, 256, 0, stream>>>(ei2 + E2_N, cnt2, E2_N);
    scan_blocks_both<<<NP1 + NP2, 256, 0, stream>>>(cnt1, off1, part1, cnt2, off2, part2);
    scan_partials_both<<<1, 256, 0, stream>>>(part1, off1 + N_TGT1, part2, off2 + N_TGT2);
    add_off_both<<<NP1 + NP2, 256, 0, stream>>>(off1, part1, cnt1, off2, part2, cnt2);
    fill_both<<<HB1 + HB2, 256, 0, stream>>>(
        ei1, ei1 + E1_N, cnt1, esrc1, ei2, ei2 + E2_N, cnt2, esrc2);

    // ---- layer 1 ----
    aggregate_bf16_256<<<(N_TGT1 + 3) / 4, 256, 0, stream>>>(esrc1, off1, xb, seg1b, N_TGT1);
    gemm_mfma<64, 192, 2, 4><<<(N_TGT1 + 63) / 64, 512, 0, stream>>>(
        seg1b, F_IN, xb, F_IN, wc1, bl1, h1b, nullptr, N_TGT1, 1);

    // ---- layer 2 ----
    aggregate_bf16_192<<<(N_TGT2 + 3) / 4, 256, 0, stream>>>(esrc2, off2, h1b, seg2b, N_TGT2);

    // fused tail: gemm2 + gemm3(emb) + gemm4(logits) + log_softmax
    tail_fused<<<(N_TGT2 + 63) / 64, 512, 0, stream>>>(
        seg2b, h1b, wc2, bl2, w1b, b1, w2b, b2, out_emb, out_ls, N_TGT2);
}